// Round 13
// baseline (574.903 us; speedup 1.0000x reference)
//
#include <hip/hip_runtime.h>
#include <hip/hip_bf16.h>

#define AS1 __attribute__((address_space(1)))
#define AS3 __attribute__((address_space(3)))

__constant__ float c_mean[3] = {0.485f, 0.456f, 0.406f};
__constant__ float c_istd[3] = {1.0f/0.229f, 1.0f/0.224f, 1.0f/0.225f};

typedef __attribute__((ext_vector_type(8))) short short8;
typedef __attribute__((ext_vector_type(4))) float floatv4;
typedef unsigned short ushort;

__device__ inline float bf2f(ushort u) {
  unsigned int x = ((unsigned int)u) << 16;
  float f; __builtin_memcpy(&f, &x, 4); return f;
}
__device__ inline ushort f2bf(float f) {
  __hip_bfloat16 h = __float2bfloat16(f);
  ushort u; __builtin_memcpy(&u, &h, 2); return u;
}

// ---------------- zero ssq accumulators + zero-page ----------------
__global__ __launch_bounds__(256) void zero_k(float* __restrict__ p, int n)
{
  int i = blockIdx.x * 256 + threadIdx.x;
  if (i < n) p[i] = 0.f;
}

// ---------------- all weight transforms in ONE kernel ----------------
__device__ inline void wtr(const float* w, ushort* Wp, int OC, int IC, int t)
{
  int total = OC * IC * 9;
  if (t >= total) return;
  int oct16 = OC >> 4;
  int j = t & 7;
  int L = (t >> 3) & 63;
  int f = t >> 9;
  int ot = f % oct16;
  int r  = f / oct16;
  int tap = r % 9;
  int kc  = r / 9;
  int oc = ot * 16 + (L & 15);
  int ic = kc * 32 + ((L >> 4) << 3) + j;
  Wp[(size_t)f * 512 + L * 8 + j] = f2bf(w[((size_t)oc * IC + ic) * 9 + tap]);
}

__global__ __launch_bounds__(256) void wtrans_all_k(
    const float* w1, const float* w2, const float* w3,
    const float* w4, const float* w5, const float* w6,
    ushort* W1, ushort* W2, ushort* W3, ushort* W4, ushort* W5, ushort* W6)
{
  int blk = blockIdx.x;
  int tid = threadIdx.x;
  if      (blk < 144)  wtr(w1, W1, 64,  64,  blk * 256 + tid);
  else if (blk < 432)  wtr(w2, W2, 128, 64,  (blk - 144) * 256 + tid);
  else if (blk < 1008) wtr(w3, W3, 128, 128, (blk - 432) * 256 + tid);
  else if (blk < 2160) wtr(w4, W4, 256, 128, (blk - 1008) * 256 + tid);
  else if (blk < 4464) wtr(w5, W5, 256, 256, (blk - 2160) * 256 + tid);
  else                 wtr(w6, W6, 256, 256, (blk - 4464) * 256 + tid);
}

// ---------------- conv1_1: IC=3 direct fp32, batch 8 (outputs||styles), out NHWC bf16 ----------------
__global__ __launch_bounds__(256) void conv0_k(const float* __restrict__ imgA,
                                               const float* __restrict__ imgB,
                                               const float* __restrict__ w,
                                               const float* __restrict__ bias,
                                               ushort* __restrict__ Yh)
{
  __shared__ float wl[27][64];
  __shared__ float bl[64];
  const int tid = threadIdx.x;
  for (int i = tid; i < 1728; i += 256) {
    int o = i & 63, t = i >> 6;
    wl[t][o] = w[o * 27 + t];
  }
  if (tid < 64) bl[tid] = bias[tid];
  __syncthreads();
  int px = blockIdx.x * 256 + tid;
  int b = px >> 16, rem = px & 65535;
  int y = rem >> 8, x = rem & 255;
  const float* img = (b < 4) ? (imgA + (size_t)b * 3 * 65536)
                             : (imgB + (size_t)(b - 4) * 3 * 65536);
  float iv[27];
#pragma unroll
  for (int c = 0; c < 3; ++c)
#pragma unroll
    for (int dy = 0; dy < 3; ++dy)
#pragma unroll
      for (int dx = 0; dx < 3; ++dx) {
        int gy = y - 1 + dy, gx = x - 1 + dx;
        float v = 0.f;
        if (gy >= 0 && gy < 256 && gx >= 0 && gx < 256)
          v = (img[(size_t)c * 65536 + gy * 256 + gx] - c_mean[c]) * c_istd[c];
        iv[c * 9 + dy * 3 + dx] = v;
      }
  float acc[64];
#pragma unroll
  for (int o = 0; o < 64; ++o) acc[o] = 0.f;
#pragma unroll
  for (int t = 0; t < 27; ++t) {
    float v = iv[t];
#pragma unroll
    for (int o = 0; o < 64; ++o) acc[o] = fmaf(v, wl[t][o], acc[o]);
  }
  size_t base = (size_t)px * 64;
#pragma unroll
  for (int o8 = 0; o8 < 8; ++o8) {
    short8 vh;
#pragma unroll
    for (int j = 0; j < 8; ++j)
      vh[j] = (short)f2bf(fmaxf(acc[o8 * 8 + j] + bl[o8 * 8 + j], 0.f));
    *(short8*)(Yh + base + o8 * 8) = vh;
  }
}

// ---------------- MFMA implicit-GEMM 3x3 conv, pure bf16, async-LDS double-buffered ------------
// TM = oc-fragments per wave (4 -> 64oc, 8 -> 128oc: halves A LDS reads + halo staging per output).
// global_load_lds staging (lane-contiguous LDS [px][icq][8k]), ONE barrier per 32-k chunk.
// TIN/TOUT: input/output in MFMA-tiled cat layout [b][n>>4][kc][n&15][8]; else NHWC.
template<int TH, int WPY, int WPO, int TM, bool POOL, bool SSQ, bool TIN, bool TOUT>
__global__ __launch_bounds__(256) void convmf_k(
    const ushort* __restrict__ Xh,
    const ushort* __restrict__ Wp,
    const float* __restrict__ bias,
    ushort* __restrict__ Yh,
    float* __restrict__ ssq,
    const ushort* __restrict__ zpage,
    int H, int W, int IC, int in_stride, int ic_off,
    int OC, int out_stride, int oc_off, int octiles)
{
  constexpr int HR = TH + 2;
  constexpr int HALO = HR * 18;
  constexpr int NJ = (HALO * 4 + 255) / 256;
  constexpr int SLOTS = NJ * 256;
  constexpr int OCB = WPO * TM * 16;
  __shared__ ushort xs[2][SLOTS * 8];

  const int tid = threadIdx.x;
  const int wave = tid >> 6, lane = tid & 63;
  const int quad = lane >> 4, l16 = lane & 15;
  const int wy = wave / WPO, wo = wave % WPO;
  const int bb = blockIdx.z / octiles, ot = blockIdx.z % octiles;
  const int y0 = blockIdx.y * TH, x0 = blockIdx.x * 16;
  const int ocbase = ot * OCB + wo * TM * 16;
  const int oct16 = OC >> 4;

  const ushort* gb[NJ];
  int stp[NJ];
#pragma unroll
  for (int j = 0; j < NJ; ++j) {
    int u = tid + j * 256;
    int px = u >> 2, icq = u & 3;
    int hy = px / 18, hx = px - hy * 18;
    int gy = y0 - 1 + hy, gx = x0 - 1 + hx;
    bool valid = (gy >= 0 && gy < H && gx >= 0 && gx < W);
    int cgy = valid ? gy : 0, cgx = valid ? gx : 0;
    size_t g0;
    if (TIN) {
      int tile = bb * ((H * W) >> 4) + cgy * (W >> 4) + (cgx >> 4);
      g0 = (((size_t)tile * (in_stride >> 3) + (ic_off >> 3) + icq) << 7) + ((cgx & 15) << 3);
    } else {
      g0 = ((size_t)(bb * H + cgy) * W + cgx) * in_stride + ic_off + icq * 8;
    }
    gb[j]  = valid ? (Xh + g0) : zpage;
    stp[j] = valid ? (TIN ? 16 : 1) : 0;
  }

  floatv4 acc[4][TM];
#pragma unroll
  for (int tn = 0; tn < 4; ++tn)
#pragma unroll
    for (int tm = 0; tm < TM; ++tm) acc[tn][tm] = (floatv4){0.f, 0.f, 0.f, 0.f};

  const int NC = IC >> 5;

#pragma unroll
  for (int j = 0; j < NJ; ++j)
    __builtin_amdgcn_global_load_lds((AS1 const void*)gb[j],
        (AS3 void*)&xs[0][(size_t)(tid + j * 256) * 8], 16, 0, 0);

  for (int ci = 0; ci < NC; ++ci) {
    __syncthreads();
    if (ci + 1 < NC) {
      const int k0n = (ci + 1) * 32;
      const int nbuf = (ci + 1) & 1;
#pragma unroll
      for (int j = 0; j < NJ; ++j)
        __builtin_amdgcn_global_load_lds((AS1 const void*)(gb[j] + (size_t)k0n * stp[j]),
            (AS3 void*)&xs[nbuf][(size_t)(tid + j * 256) * 8], 16, 0, 0);
    }
    const ushort* xsc = xs[ci & 1];
    const int k0 = ci * 32;

#pragma unroll
    for (int tap = 0; tap < 9; ++tap) {
      const int dy = tap / 3, dx = tap % 3;
      const size_t wg = (((size_t)(k0 >> 5) * 9 + tap) * oct16 + (ocbase >> 4)) * 512 + (size_t)lane * 8;
      short8 bh[TM];
#pragma unroll
      for (int tm = 0; tm < TM; ++tm)
        bh[tm] = *(const short8*)(Wp + wg + tm * 512);
#pragma unroll
      for (int tn = 0; tn < 4; ++tn) {
        int p = wy * 64 + tn * 16 + l16;
        int ty = p >> 4, tx = p & 15;
        int hp = (ty + dy) * 18 + tx + dx;
        short8 ah = *(const short8*)&xsc[(size_t)(hp * 4 + quad) * 8];
#pragma unroll
        for (int tm = 0; tm < TM; ++tm)
          acc[tn][tm] = __builtin_amdgcn_mfma_f32_16x16x32_bf16(ah, bh[tm], acc[tn][tm], 0, 0, 0);
      }
    }
  }

  if (POOL) {
    const int oH = H >> 1, oW = W >> 1;
#pragma unroll
    for (int tm = 0; tm < TM; ++tm) {
      int ocg = ocbase + tm * 16 + l16;
      float bv = bias[ocg];
#pragma unroll
      for (int tn2 = 0; tn2 < 2; ++tn2)
#pragma unroll
        for (int r2 = 0; r2 < 2; ++r2) {
          float v0 = fmaxf(acc[2 * tn2][tm][2 * r2]     + bv, 0.f);
          float v1 = fmaxf(acc[2 * tn2][tm][2 * r2 + 1] + bv, 0.f);
          float v2 = fmaxf(acc[2 * tn2 + 1][tm][2 * r2]     + bv, 0.f);
          float v3 = fmaxf(acc[2 * tn2 + 1][tm][2 * r2 + 1] + bv, 0.f);
          float v = fmaxf(fmaxf(v0, v1), fmaxf(v2, v3));
          int oy = (y0 >> 1) + wy * 2 + tn2;
          int ox = (x0 >> 1) + quad * 2 + r2;
          Yh[((size_t)(bb * oH + oy) * oW + ox) * out_stride + oc_off + ocg] = f2bf(v);
        }
    }
  } else {
    float sv[4][4];
    if (SSQ) {
#pragma unroll
      for (int tn = 0; tn < 4; ++tn)
#pragma unroll
        for (int r = 0; r < 4; ++r) sv[tn][r] = 0.f;
    }
#pragma unroll
    for (int tm = 0; tm < TM; ++tm) {
      int ocg = ocbase + tm * 16 + l16;
      float bv = bias[ocg];
#pragma unroll
      for (int tn = 0; tn < 4; ++tn)
#pragma unroll
        for (int r = 0; r < 4; ++r) {
          int p = wy * 64 + tn * 16 + quad * 4 + r;
          int ty = p >> 4, tx = p & 15;
          float v = fmaxf(acc[tn][tm][r] + bv, 0.f);
          ushort h = f2bf(v);
          if (SSQ) { float vr = bf2f(h); sv[tn][r] = fmaf(vr, vr, sv[tn][r]); }
          size_t o;
          if (TOUT) {
            int n_out = (y0 + ty) * W + x0 + tx;
            int oc = oc_off + ocg;
            o = (((size_t)(bb * ((H * W) >> 4) + (n_out >> 4)) * (out_stride >> 3) + (oc >> 3)) << 7)
                + ((n_out & 15) << 3) + (oc & 7);
          } else {
            o = ((size_t)(bb * H + y0 + ty) * W + x0 + tx) * out_stride + oc_off + ocg;
          }
          Yh[o] = h;
        }
    }
    if (SSQ) {
#pragma unroll
      for (int tn = 0; tn < 4; ++tn)
#pragma unroll
        for (int r = 0; r < 4; ++r) {
          float s = sv[tn][r];
          s += __shfl_xor(s, 1, 64);
          s += __shfl_xor(s, 2, 64);
          s += __shfl_xor(s, 4, 64);
          s += __shfl_xor(s, 8, 64);
          if (l16 == 0) {
            int p = wy * 64 + tn * 16 + quad * 4 + r;
            int ty = p >> 4, tx = p & 15;
            atomicAdd(&ssq[(size_t)bb * 4096 + (y0 + ty) * 64 + x0 + tx], s);
          }
        }
    }
  }
}

// ---------------- fused sim-max GEMM, barrier-free K-loop (r10/r11 grid: n0 = bx) ----------------
__global__ __launch_bounds__(256) void simmax_k(
    const ushort* __restrict__ Ct,
    const float* __restrict__ ssqs, float* __restrict__ partial)
{
  __shared__ float redbuf[2][128];
  const int tid = threadIdx.x;
  const int lane = tid & 63, wave = tid >> 6;
  const int quad = lane >> 4, l16 = lane & 15;
  const int wn0 = (wave >> 1) * 64;
  const int wm0 = (wave & 1) * 64;
  const int n0 = blockIdx.x * 128;
  const int ms = blockIdx.y;
  const int b  = blockIdx.z;

  float runmax[4][4];
#pragma unroll
  for (int tn = 0; tn < 4; ++tn)
#pragma unroll
    for (int r = 0; r < 4; ++r) runmax[tn][r] = -1e30f;

  const ushort* xbase = Ct + (((size_t)(b * 256 + (n0 >> 4) + (wn0 >> 4)) * 96) << 7) + ((size_t)l16 << 3);

  for (int mc = 0; mc < 4; ++mc) {
    const ushort* sbase = Ct + (((size_t)((b + 4) * 256 + ms * 32 + mc * 8 + (wm0 >> 4)) * 96) << 7) + ((size_t)l16 << 3);
    floatv4 acc[4][4];
#pragma unroll
    for (int tn = 0; tn < 4; ++tn)
#pragma unroll
      for (int tm = 0; tm < 4; ++tm) acc[tn][tm] = (floatv4){0.f, 0.f, 0.f, 0.f};

#pragma unroll 2
    for (int kc0 = 0; kc0 < 96; kc0 += 4) {
      short8 ah[4], bh[4];
#pragma unroll
      for (int t = 0; t < 4; ++t)
        ah[t] = *(const short8*)(xbase + (((size_t)t * 96 + kc0 + quad) << 7));
#pragma unroll
      for (int t = 0; t < 4; ++t)
        bh[t] = *(const short8*)(sbase + (((size_t)t * 96 + kc0 + quad) << 7));
#pragma unroll
      for (int tn = 0; tn < 4; ++tn)
#pragma unroll
        for (int tm = 0; tm < 4; ++tm)
          acc[tn][tm] = __builtin_amdgcn_mfma_f32_16x16x32_bf16(ah[tn], bh[tm], acc[tn][tm], 0, 0, 0);
    }

    const int m0 = ms * 512 + mc * 128;
#pragma unroll
    for (int tm = 0; tm < 4; ++tm) {
      float sq = ssqs[(size_t)b * 4096 + m0 + wm0 + tm * 16 + l16];
      float inv = 1.0f / (sqrtf(sq) + 1e-8f);
#pragma unroll
      for (int tn = 0; tn < 4; ++tn)
#pragma unroll
        for (int r = 0; r < 4; ++r)
          runmax[tn][r] = fmaxf(runmax[tn][r], acc[tn][tm][r] * inv);
    }
  }

#pragma unroll
  for (int off = 1; off < 16; off <<= 1)
#pragma unroll
    for (int tn = 0; tn < 4; ++tn)
#pragma unroll
      for (int r = 0; r < 4; ++r)
        runmax[tn][r] = fmaxf(runmax[tn][r], __shfl_xor(runmax[tn][r], off, 64));

  if (l16 == 0) {
#pragma unroll
    for (int tn = 0; tn < 4; ++tn)
#pragma unroll
      for (int r = 0; r < 4; ++r)
        redbuf[wave & 1][wn0 + tn * 16 + quad * 4 + r] = runmax[tn][r];
  }
  __syncthreads();
  if (tid < 128) {
    float mx = fmaxf(redbuf[0][tid], redbuf[1][tid]);
    partial[((size_t)ms * 4 + b) * 4096 + n0 + tid] = mx;
  }
}

// ---------------- final: combine 8 partials, inline invnx from ssq, mean ----------------
__global__ __launch_bounds__(256) void loss_k(const float* __restrict__ partial,
                                              const float* __restrict__ ssqx,
                                              float* __restrict__ out)
{
  float sum = 0.f;
  for (int i = threadIdx.x; i < 16384; i += 256) {
    float mx = partial[i];
#pragma unroll
    for (int j = 1; j < 8; ++j) mx = fmaxf(mx, partial[j * 16384 + i]);
    sum += mx * (1.0f / (sqrtf(ssqx[i]) + 1e-8f));
  }
  __shared__ float red[256];
  red[threadIdx.x] = sum;
  __syncthreads();
  for (int s = 128; s > 0; s >>= 1) {
    if (threadIdx.x < s) red[threadIdx.x] += red[threadIdx.x + s];
    __syncthreads();
  }
  if (threadIdx.x == 0) out[0] = 1.f - red[0] * (1.f / 16384.f);
}

extern "C" void kernel_launch(void* const* d_in, const int* in_sizes, int n_in,
                              void* d_out, int out_size, void* d_ws, size_t ws_size,
                              hipStream_t stream)
{
  const float* outputs = (const float*)d_in[0];
  const float* styles  = (const float*)d_in[1];
  const float* w[7]; const float* bs[7];
  for (int i = 0; i < 7; ++i) { w[i] = (const float*)d_in[2 + 2 * i]; bs[i] = (const float*)d_in[3 + 2 * i]; }

  // ---- workspace layout (ushort units) ----
  ushort* p = (ushort*)d_ws;
  ushort* A_h = p; p += 33554432;     // 8*256*256*64 (conv1_1 out) == 8*128*128*128 (conv2_1 out)
  ushort* B_h = p; p += 8388608;      // 8*128*128*64 / 8*64*64*128
  ushort* cat_h = p; p += 25165824;   // 8*4096*768, MFMA-tiled [b][n>>4][kc][n&15][8]
  ushort* W1p = p; p += 36864;
  ushort* W2p = p; p += 73728;
  ushort* W3p = p; p += 147456;
  ushort* W4p = p; p += 294912;
  ushort* W5p = p; p += 589824;
  ushort* W6p = p; p += 589824;
  float* nrm = (float*)p;             // 8*4096 ssq (x then s)
  float* zpage = nrm + 32768;         // 1024 floats of zeros (staging OOB target)
  float* partial = zpage + 1024;      // 8*4*4096

  zero_k<<<dim3(132), 256, 0, stream>>>(nrm, 33792);

  wtrans_all_k<<<dim3(6768), 256, 0, stream>>>(w[1], w[2], w[3], w[4], w[5], w[6],
                                               W1p, W2p, W3p, W4p, W5p, W6p);

  // conv1_1 batch 8 (outputs || styles)
  conv0_k<<<dim3(2048), 256, 0, stream>>>(outputs, styles, w[0], bs[0], A_h);
  // conv1_2 + pool (OC=64, TM=4): 8x256x256x64 -> 8x128x128x64
  convmf_k<16,4,1,4,true,false,false,false><<<dim3(16,16,8), 256, 0, stream>>>(A_h, W1p, bs[1],
      B_h, nullptr, (const ushort*)zpage, 256,256, 64, 64,0, 64, 64,0, 1);
  // conv2_1 (TM=8, 128oc/wave): -> 8x128x128x128
  convmf_k<16,4,1,8,false,false,false,false><<<dim3(8,8,8), 256, 0, stream>>>(B_h, W2p, bs[2],
      A_h, nullptr, (const ushort*)zpage, 128,128, 64, 64,0, 128, 128,0, 1);
  // conv2_2 + pool (TM=8): -> 8x64x64x128
  convmf_k<16,4,1,8,true,false,false,false><<<dim3(8,8,8), 256, 0, stream>>>(A_h, W3p, bs[3],
      B_h, nullptr, (const ushort*)zpage, 128,128, 128, 128,0, 128, 128,0, 1);
  // conv3_1 (TM=8, octiles=2): -> cat[:, 0:256] (tiled out), fused ssq
  convmf_k<16,4,1,8,false,true,false,true><<<dim3(4,4,16), 256, 0, stream>>>(B_h, W4p, bs[4],
      cat_h, nrm, (const ushort*)zpage, 64,64, 128, 128,0, 256, 768,0, 2);
  // conv3_2 (TM=8): cat[0:256] -> cat[256:512] (tiled in+out)
  convmf_k<16,4,1,8,false,true,true,true><<<dim3(4,4,16), 256, 0, stream>>>(cat_h, W5p, bs[5],
      cat_h, nrm, (const ushort*)zpage, 64,64, 256, 768,0, 256, 768,256, 2);
  // conv3_3 (TM=8): cat[256:512] -> cat[512:768] (tiled in+out)
  convmf_k<16,4,1,8,false,true,true,true><<<dim3(4,4,16), 256, 0, stream>>>(cat_h, W6p, bs[6],
      cat_h, nrm, (const ushort*)zpage, 64,64, 256, 768,256, 256, 768,512, 2);

  // sim-max (reverted locality-correct grid) + loss
  simmax_k<<<dim3(32, 8, 4), 256, 0, stream>>>(cat_h, nrm + 16384, partial);
  loss_k<<<dim3(1), 256, 0, stream>>>(partial, nrm, (float*)d_out);
}

// Round 14
// 530.507 us; speedup vs baseline: 1.0837x; 1.0837x over previous
//
#include <hip/hip_runtime.h>
#include <hip/hip_bf16.h>

#define AS1 __attribute__((address_space(1)))
#define AS3 __attribute__((address_space(3)))

__constant__ float c_mean[3] = {0.485f, 0.456f, 0.406f};
__constant__ float c_istd[3] = {1.0f/0.229f, 1.0f/0.224f, 1.0f/0.225f};

typedef __attribute__((ext_vector_type(8))) short short8;
typedef __attribute__((ext_vector_type(4))) float floatv4;
typedef unsigned short ushort;

__device__ inline float bf2f(ushort u) {
  unsigned int x = ((unsigned int)u) << 16;
  float f; __builtin_memcpy(&f, &x, 4); return f;
}
__device__ inline ushort f2bf(float f) {
  __hip_bfloat16 h = __float2bfloat16(f);
  ushort u; __builtin_memcpy(&u, &h, 2); return u;
}

// ---------------- zero ssq accumulators + zero-page ----------------
__global__ __launch_bounds__(256) void zero_k(float* __restrict__ p, int n)
{
  int i = blockIdx.x * 256 + threadIdx.x;
  if (i < n) p[i] = 0.f;
}

// ---------------- all weight transforms in ONE kernel ----------------
__device__ inline void wtr(const float* w, ushort* Wp, int OC, int IC, int t)
{
  int total = OC * IC * 9;
  if (t >= total) return;
  int oct16 = OC >> 4;
  int j = t & 7;
  int L = (t >> 3) & 63;
  int f = t >> 9;
  int ot = f % oct16;
  int r  = f / oct16;
  int tap = r % 9;
  int kc  = r / 9;
  int oc = ot * 16 + (L & 15);
  int ic = kc * 32 + ((L >> 4) << 3) + j;
  Wp[(size_t)f * 512 + L * 8 + j] = f2bf(w[((size_t)oc * IC + ic) * 9 + tap]);
}

__global__ __launch_bounds__(256) void wtrans_all_k(
    const float* w1, const float* w2, const float* w3,
    const float* w4, const float* w5, const float* w6,
    ushort* W1, ushort* W2, ushort* W3, ushort* W4, ushort* W5, ushort* W6)
{
  int blk = blockIdx.x;
  int tid = threadIdx.x;
  if      (blk < 144)  wtr(w1, W1, 64,  64,  blk * 256 + tid);
  else if (blk < 432)  wtr(w2, W2, 128, 64,  (blk - 144) * 256 + tid);
  else if (blk < 1008) wtr(w3, W3, 128, 128, (blk - 432) * 256 + tid);
  else if (blk < 2160) wtr(w4, W4, 256, 128, (blk - 1008) * 256 + tid);
  else if (blk < 4464) wtr(w5, W5, 256, 256, (blk - 2160) * 256 + tid);
  else                 wtr(w6, W6, 256, 256, (blk - 4464) * 256 + tid);
}

// ---------------- conv1_1: IC=3 direct fp32, batch 8 (outputs||styles), out NHWC bf16 ----------------
__global__ __launch_bounds__(256) void conv0_k(const float* __restrict__ imgA,
                                               const float* __restrict__ imgB,
                                               const float* __restrict__ w,
                                               const float* __restrict__ bias,
                                               ushort* __restrict__ Yh)
{
  __shared__ float wl[27][64];
  __shared__ float bl[64];
  const int tid = threadIdx.x;
  for (int i = tid; i < 1728; i += 256) {
    int o = i & 63, t = i >> 6;
    wl[t][o] = w[o * 27 + t];
  }
  if (tid < 64) bl[tid] = bias[tid];
  __syncthreads();
  int px = blockIdx.x * 256 + tid;
  int b = px >> 16, rem = px & 65535;
  int y = rem >> 8, x = rem & 255;
  const float* img = (b < 4) ? (imgA + (size_t)b * 3 * 65536)
                             : (imgB + (size_t)(b - 4) * 3 * 65536);
  float iv[27];
#pragma unroll
  for (int c = 0; c < 3; ++c)
#pragma unroll
    for (int dy = 0; dy < 3; ++dy)
#pragma unroll
      for (int dx = 0; dx < 3; ++dx) {
        int gy = y - 1 + dy, gx = x - 1 + dx;
        float v = 0.f;
        if (gy >= 0 && gy < 256 && gx >= 0 && gx < 256)
          v = (img[(size_t)c * 65536 + gy * 256 + gx] - c_mean[c]) * c_istd[c];
        iv[c * 9 + dy * 3 + dx] = v;
      }
  float acc[64];
#pragma unroll
  for (int o = 0; o < 64; ++o) acc[o] = 0.f;
#pragma unroll
  for (int t = 0; t < 27; ++t) {
    float v = iv[t];
#pragma unroll
    for (int o = 0; o < 64; ++o) acc[o] = fmaf(v, wl[t][o], acc[o]);
  }
  size_t base = (size_t)px * 64;
#pragma unroll
  for (int o8 = 0; o8 < 8; ++o8) {
    short8 vh;
#pragma unroll
    for (int j = 0; j < 8; ++j)
      vh[j] = (short)f2bf(fmaxf(acc[o8 * 8 + j] + bl[o8 * 8 + j], 0.f));
    *(short8*)(Yh + base + o8 * 8) = vh;
  }
}

// ---------------- MFMA implicit-GEMM 3x3 conv, pure bf16, async-LDS double-buffered ------------
// r12 config (TM=4): best measured conv structure. global_load_lds staging (lane-contiguous
// LDS [px][icq][8k]), ONE barrier per 32-k chunk: next chunk's DMA flies during compute.
// TIN/TOUT: input/output in MFMA-tiled cat layout [b][n>>4][kc][n&15][8]; else NHWC.
template<int TH, int WPY, int WPO, bool POOL, bool SSQ, bool TIN, bool TOUT>
__global__ __launch_bounds__(256) void convmf_k(
    const ushort* __restrict__ Xh,
    const ushort* __restrict__ Wp,
    const float* __restrict__ bias,
    ushort* __restrict__ Yh,
    float* __restrict__ ssq,
    const ushort* __restrict__ zpage,
    int H, int W, int IC, int in_stride, int ic_off,
    int OC, int out_stride, int oc_off, int octiles)
{
  constexpr int HR = TH + 2;
  constexpr int HALO = HR * 18;
  constexpr int NJ = (HALO * 4 + 255) / 256;
  constexpr int SLOTS = NJ * 256;
  __shared__ ushort xs[2][SLOTS * 8];

  const int tid = threadIdx.x;
  const int wave = tid >> 6, lane = tid & 63;
  const int quad = lane >> 4, l16 = lane & 15;
  const int wy = wave / WPO, wo = wave % WPO;
  const int bb = blockIdx.z / octiles, ot = blockIdx.z % octiles;
  const int y0 = blockIdx.y * TH, x0 = blockIdx.x * 16;
  const int ocbase = ot * (WPO * 64) + wo * 64;
  const int oct16 = OC >> 4;

  const ushort* gb[NJ];
  int stp[NJ];
#pragma unroll
  for (int j = 0; j < NJ; ++j) {
    int u = tid + j * 256;
    int px = u >> 2, icq = u & 3;
    int hy = px / 18, hx = px - hy * 18;
    int gy = y0 - 1 + hy, gx = x0 - 1 + hx;
    bool valid = (gy >= 0 && gy < H && gx >= 0 && gx < W);
    int cgy = valid ? gy : 0, cgx = valid ? gx : 0;
    size_t g0;
    if (TIN) {
      int tile = bb * ((H * W) >> 4) + cgy * (W >> 4) + (cgx >> 4);
      g0 = (((size_t)tile * (in_stride >> 3) + (ic_off >> 3) + icq) << 7) + ((cgx & 15) << 3);
    } else {
      g0 = ((size_t)(bb * H + cgy) * W + cgx) * in_stride + ic_off + icq * 8;
    }
    gb[j]  = valid ? (Xh + g0) : zpage;
    stp[j] = valid ? (TIN ? 16 : 1) : 0;
  }

  floatv4 acc[4][4];
#pragma unroll
  for (int tn = 0; tn < 4; ++tn)
#pragma unroll
    for (int tm = 0; tm < 4; ++tm) acc[tn][tm] = (floatv4){0.f, 0.f, 0.f, 0.f};

  const int NC = IC >> 5;

#pragma unroll
  for (int j = 0; j < NJ; ++j)
    __builtin_amdgcn_global_load_lds((AS1 const void*)gb[j],
        (AS3 void*)&xs[0][(size_t)(tid + j * 256) * 8], 16, 0, 0);

  for (int ci = 0; ci < NC; ++ci) {
    __syncthreads();
    if (ci + 1 < NC) {
      const int k0n = (ci + 1) * 32;
      const int nbuf = (ci + 1) & 1;
#pragma unroll
      for (int j = 0; j < NJ; ++j)
        __builtin_amdgcn_global_load_lds((AS1 const void*)(gb[j] + (size_t)k0n * stp[j]),
            (AS3 void*)&xs[nbuf][(size_t)(tid + j * 256) * 8], 16, 0, 0);
    }
    const ushort* xsc = xs[ci & 1];
    const int k0 = ci * 32;

#pragma unroll
    for (int tap = 0; tap < 9; ++tap) {
      const int dy = tap / 3, dx = tap % 3;
      const size_t wg = (((size_t)(k0 >> 5) * 9 + tap) * oct16 + (ocbase >> 4)) * 512 + (size_t)lane * 8;
      short8 bh[4];
#pragma unroll
      for (int tm = 0; tm < 4; ++tm)
        bh[tm] = *(const short8*)(Wp + wg + tm * 512);
#pragma unroll
      for (int tn = 0; tn < 4; ++tn) {
        int p = wy * 64 + tn * 16 + l16;
        int ty = p >> 4, tx = p & 15;
        int hp = (ty + dy) * 18 + tx + dx;
        short8 ah = *(const short8*)&xsc[(size_t)(hp * 4 + quad) * 8];
#pragma unroll
        for (int tm = 0; tm < 4; ++tm)
          acc[tn][tm] = __builtin_amdgcn_mfma_f32_16x16x32_bf16(ah, bh[tm], acc[tn][tm], 0, 0, 0);
      }
    }
  }

  if (POOL) {
    const int oH = H >> 1, oW = W >> 1;
#pragma unroll
    for (int tm = 0; tm < 4; ++tm) {
      int ocg = ocbase + tm * 16 + l16;
      float bv = bias[ocg];
#pragma unroll
      for (int tn2 = 0; tn2 < 2; ++tn2)
#pragma unroll
        for (int r2 = 0; r2 < 2; ++r2) {
          float v0 = fmaxf(acc[2 * tn2][tm][2 * r2]     + bv, 0.f);
          float v1 = fmaxf(acc[2 * tn2][tm][2 * r2 + 1] + bv, 0.f);
          float v2 = fmaxf(acc[2 * tn2 + 1][tm][2 * r2]     + bv, 0.f);
          float v3 = fmaxf(acc[2 * tn2 + 1][tm][2 * r2 + 1] + bv, 0.f);
          float v = fmaxf(fmaxf(v0, v1), fmaxf(v2, v3));
          int oy = (y0 >> 1) + wy * 2 + tn2;
          int ox = (x0 >> 1) + quad * 2 + r2;
          Yh[((size_t)(bb * oH + oy) * oW + ox) * out_stride + oc_off + ocg] = f2bf(v);
        }
    }
  } else {
    float sv[4][4];
    if (SSQ) {
#pragma unroll
      for (int tn = 0; tn < 4; ++tn)
#pragma unroll
        for (int r = 0; r < 4; ++r) sv[tn][r] = 0.f;
    }
#pragma unroll
    for (int tm = 0; tm < 4; ++tm) {
      int ocg = ocbase + tm * 16 + l16;
      float bv = bias[ocg];
#pragma unroll
      for (int tn = 0; tn < 4; ++tn)
#pragma unroll
        for (int r = 0; r < 4; ++r) {
          int p = wy * 64 + tn * 16 + quad * 4 + r;
          int ty = p >> 4, tx = p & 15;
          float v = fmaxf(acc[tn][tm][r] + bv, 0.f);
          ushort h = f2bf(v);
          if (SSQ) { float vr = bf2f(h); sv[tn][r] = fmaf(vr, vr, sv[tn][r]); }
          size_t o;
          if (TOUT) {
            int n_out = (y0 + ty) * W + x0 + tx;
            int oc = oc_off + ocg;
            o = (((size_t)(bb * ((H * W) >> 4) + (n_out >> 4)) * (out_stride >> 3) + (oc >> 3)) << 7)
                + ((n_out & 15) << 3) + (oc & 7);
          } else {
            o = ((size_t)(bb * H + y0 + ty) * W + x0 + tx) * out_stride + oc_off + ocg;
          }
          Yh[o] = h;
        }
    }
    if (SSQ) {
#pragma unroll
      for (int tn = 0; tn < 4; ++tn)
#pragma unroll
        for (int r = 0; r < 4; ++r) {
          float s = sv[tn][r];
          s += __shfl_xor(s, 1, 64);
          s += __shfl_xor(s, 2, 64);
          s += __shfl_xor(s, 4, 64);
          s += __shfl_xor(s, 8, 64);
          if (l16 == 0) {
            int p = wy * 64 + tn * 16 + quad * 4 + r;
            int ty = p >> 4, tx = p & 15;
            atomicAdd(&ssq[(size_t)bb * 4096 + (y0 + ty) * 64 + x0 + tx], s);
          }
        }
    }
  }
}

// ---------------- fused sim-max GEMM, barrier-free K-loop, locality grid (32,8,4) ----------------
__global__ __launch_bounds__(256) void simmax_k(
    const ushort* __restrict__ Ct,
    const float* __restrict__ ssqs, float* __restrict__ partial)
{
  __shared__ float redbuf[2][128];
  const int tid = threadIdx.x;
  const int lane = tid & 63, wave = tid >> 6;
  const int quad = lane >> 4, l16 = lane & 15;
  const int wn0 = (wave >> 1) * 64;
  const int wm0 = (wave & 1) * 64;
  const int n0 = blockIdx.x * 128;
  const int ms = blockIdx.y;
  const int b  = blockIdx.z;

  float runmax[4][4];
#pragma unroll
  for (int tn = 0; tn < 4; ++tn)
#pragma unroll
    for (int r = 0; r < 4; ++r) runmax[tn][r] = -1e30f;

  const ushort* xbase = Ct + (((size_t)(b * 256 + (n0 >> 4) + (wn0 >> 4)) * 96) << 7) + ((size_t)l16 << 3);

  for (int mc = 0; mc < 4; ++mc) {
    const ushort* sbase = Ct + (((size_t)((b + 4) * 256 + ms * 32 + mc * 8 + (wm0 >> 4)) * 96) << 7) + ((size_t)l16 << 3);
    floatv4 acc[4][4];
#pragma unroll
    for (int tn = 0; tn < 4; ++tn)
#pragma unroll
      for (int tm = 0; tm < 4; ++tm) acc[tn][tm] = (floatv4){0.f, 0.f, 0.f, 0.f};

#pragma unroll 2
    for (int kc0 = 0; kc0 < 96; kc0 += 4) {
      short8 ah[4], bh[4];
#pragma unroll
      for (int t = 0; t < 4; ++t)
        ah[t] = *(const short8*)(xbase + (((size_t)t * 96 + kc0 + quad) << 7));
#pragma unroll
      for (int t = 0; t < 4; ++t)
        bh[t] = *(const short8*)(sbase + (((size_t)t * 96 + kc0 + quad) << 7));
#pragma unroll
      for (int tn = 0; tn < 4; ++tn)
#pragma unroll
        for (int tm = 0; tm < 4; ++tm)
          acc[tn][tm] = __builtin_amdgcn_mfma_f32_16x16x32_bf16(ah[tn], bh[tm], acc[tn][tm], 0, 0, 0);
    }

    const int m0 = ms * 512 + mc * 128;
#pragma unroll
    for (int tm = 0; tm < 4; ++tm) {
      float sq = ssqs[(size_t)b * 4096 + m0 + wm0 + tm * 16 + l16];
      float inv = 1.0f / (sqrtf(sq) + 1e-8f);
#pragma unroll
      for (int tn = 0; tn < 4; ++tn)
#pragma unroll
        for (int r = 0; r < 4; ++r)
          runmax[tn][r] = fmaxf(runmax[tn][r], acc[tn][tm][r] * inv);
    }
  }

#pragma unroll
  for (int off = 1; off < 16; off <<= 1)
#pragma unroll
    for (int tn = 0; tn < 4; ++tn)
#pragma unroll
      for (int r = 0; r < 4; ++r)
        runmax[tn][r] = fmaxf(runmax[tn][r], __shfl_xor(runmax[tn][r], off, 64));

  if (l16 == 0) {
#pragma unroll
    for (int tn = 0; tn < 4; ++tn)
#pragma unroll
      for (int r = 0; r < 4; ++r)
        redbuf[wave & 1][wn0 + tn * 16 + quad * 4 + r] = runmax[tn][r];
  }
  __syncthreads();
  if (tid < 128) {
    float mx = fmaxf(redbuf[0][tid], redbuf[1][tid]);
    partial[((size_t)ms * 4 + b) * 4096 + n0 + tid] = mx;
  }
}

// ---------------- final: combine 8 partials, inline invnx from ssq, mean ----------------
__global__ __launch_bounds__(256) void loss_k(const float* __restrict__ partial,
                                              const float* __restrict__ ssqx,
                                              float* __restrict__ out)
{
  float sum = 0.f;
  for (int i = threadIdx.x; i < 16384; i += 256) {
    float mx = partial[i];
#pragma unroll
    for (int j = 1; j < 8; ++j) mx = fmaxf(mx, partial[j * 16384 + i]);
    sum += mx * (1.0f / (sqrtf(ssqx[i]) + 1e-8f));
  }
  __shared__ float red[256];
  red[threadIdx.x] = sum;
  __syncthreads();
  for (int s = 128; s > 0; s >>= 1) {
    if (threadIdx.x < s) red[threadIdx.x] += red[threadIdx.x + s];
    __syncthreads();
  }
  if (threadIdx.x == 0) out[0] = 1.f - red[0] * (1.f / 16384.f);
}

extern "C" void kernel_launch(void* const* d_in, const int* in_sizes, int n_in,
                              void* d_out, int out_size, void* d_ws, size_t ws_size,
                              hipStream_t stream)
{
  const float* outputs = (const float*)d_in[0];
  const float* styles  = (const float*)d_in[1];
  const float* w[7]; const float* bs[7];
  for (int i = 0; i < 7; ++i) { w[i] = (const float*)d_in[2 + 2 * i]; bs[i] = (const float*)d_in[3 + 2 * i]; }

  // ---- workspace layout (ushort units) ----
  ushort* p = (ushort*)d_ws;
  ushort* A_h = p; p += 33554432;     // 8*256*256*64 (conv1_1 out) == 8*128*128*128 (conv2_1 out)
  ushort* B_h = p; p += 8388608;      // 8*128*128*64 / 8*64*64*128
  ushort* cat_h = p; p += 25165824;   // 8*4096*768, MFMA-tiled [b][n>>4][kc][n&15][8]
  ushort* W1p = p; p += 36864;
  ushort* W2p = p; p += 73728;
  ushort* W3p = p; p += 147456;
  ushort* W4p = p; p += 294912;
  ushort* W5p = p; p += 589824;
  ushort* W6p = p; p += 589824;
  float* nrm = (float*)p;             // 8*4096 ssq (x then s)
  float* zpage = nrm + 32768;         // 1024 floats of zeros (staging OOB target)
  float* partial = zpage + 1024;      // 8*4*4096

  zero_k<<<dim3(132), 256, 0, stream>>>(nrm, 33792);

  wtrans_all_k<<<dim3(6768), 256, 0, stream>>>(w[1], w[2], w[3], w[4], w[5], w[6],
                                               W1p, W2p, W3p, W4p, W5p, W6p);

  // conv1_1 batch 8 (outputs || styles)
  conv0_k<<<dim3(2048), 256, 0, stream>>>(outputs, styles, w[0], bs[0], A_h);
  // conv1_2 + pool: 8x256x256x64 -> 8x128x128x64
  convmf_k<16,4,1,true,false,false,false><<<dim3(16,16,8), 256, 0, stream>>>(A_h, W1p, bs[1],
      B_h, nullptr, (const ushort*)zpage, 256,256, 64, 64,0, 64, 64,0, 1);
  // conv2_1: -> 8x128x128x128
  convmf_k<16,4,1,false,false,false,false><<<dim3(8,8,16), 256, 0, stream>>>(B_h, W2p, bs[2],
      A_h, nullptr, (const ushort*)zpage, 128,128, 64, 64,0, 128, 128,0, 2);
  // conv2_2 + pool: -> 8x64x64x128
  convmf_k<16,4,1,true,false,false,false><<<dim3(8,8,16), 256, 0, stream>>>(A_h, W3p, bs[3],
      B_h, nullptr, (const ushort*)zpage, 128,128, 128, 128,0, 128, 128,0, 2);
  // conv3_1: -> cat[:, 0:256] (tiled out), fused ssq
  convmf_k<16,4,1,false,true,false,true><<<dim3(4,4,32), 256, 0, stream>>>(B_h, W4p, bs[4],
      cat_h, nrm, (const ushort*)zpage, 64,64, 128, 128,0, 256, 768,0, 4);
  // conv3_2: cat[0:256] -> cat[256:512] (tiled in+out)
  convmf_k<16,4,1,false,true,true,true><<<dim3(4,4,32), 256, 0, stream>>>(cat_h, W5p, bs[5],
      cat_h, nrm, (const ushort*)zpage, 64,64, 256, 768,0, 256, 768,256, 4);
  // conv3_3: cat[256:512] -> cat[512:768] (tiled in+out)
  convmf_k<16,4,1,false,true,true,true><<<dim3(4,4,32), 256, 0, stream>>>(cat_h, W6p, bs[6],
      cat_h, nrm, (const ushort*)zpage, 64,64, 256, 768,256, 256, 768,512, 4);

  // sim-max + loss
  simmax_k<<<dim3(32, 8, 4), 256, 0, stream>>>(cat_h, nrm + 16384, partial);
  loss_k<<<dim3(1), 256, 0, stream>>>(partial, nrm, (float*)d_out);
}